// Round 19
// baseline (2479.303 us; speedup 1.0000x reference)
//
#include <hip/hip_runtime.h>
#include <hip/hip_bf16.h>

// ---------------------------------------------------------------------------
// Longformer forward, MI355X. Round 20: T5 s_setprio around attn_local's
// MFMA clusters (independent blocks at staggered phases per CU -> scheduler
// can favor MFMA-phase waves; m191 mechanism). Single change vs R18 (2479).
// Constants: B=1 NW=8 SEG=511 S=4096 W=256 C=16 H=12 D=64 DM=768 FF=3072 L=12
// ---------------------------------------------------------------------------

typedef unsigned short u16;
typedef __attribute__((ext_vector_type(4))) float floatx4;
typedef __attribute__((ext_vector_type(4))) unsigned int uintx4;
typedef __attribute__((ext_vector_type(8))) _Float16 halfx8;
typedef __attribute__((ext_vector_type(4))) u16 u16x4;

#define S_LEN 4096
#define QKVG_N 4608   // q(0) k(768) v(1536,DEAD) kg(2304) vg(3072) qg(3840)
#define NL 12

__device__ inline u16 f2h(float x) {
    union { _Float16 h; u16 u; } c; c.h = (_Float16)x; return c.u;
}
__device__ inline float h2f(u16 u) {
    union { _Float16 h; u16 u; } c; c.u = u; return (float)c.h;
}
__device__ inline float gelu_f(float x) {
    float x3 = x * x * x;
    return 0.5f * x * (1.0f + tanhf(0.7978845608028654f * (x + 0.044715f * x3)));
}

#define GLDS16(g, l)                                                              \
    __builtin_amdgcn_global_load_lds(                                             \
        (const __attribute__((address_space(1))) unsigned int*)(g),               \
        (__attribute__((address_space(3))) unsigned int*)(l), 16, 0, 0)

// ---------------------------------------------------------------------------
// Weight prep v5: fp32 [K][N] -> fp16 [N][K], all layers, one launch.
// Single [64][65] fp32 LDS; NT streams (3.7 TB/s, pattern-limited floor).
// ---------------------------------------------------------------------------
__global__ __launch_bounds__(256) void prep_weights_k(
    const float* __restrict__ Wq0, const float* __restrict__ Wk0, const float* __restrict__ Wv0,
    const float* __restrict__ Wkg0, const float* __restrict__ Wvg0, const float* __restrict__ Wqg0,
    const float* __restrict__ Wo0, const float* __restrict__ W10, const float* __restrict__ W20,
    const float* __restrict__ bq0, const float* __restrict__ bk0, const float* __restrict__ bv0,
    const float* __restrict__ bkg0, const float* __restrict__ bvg0, const float* __restrict__ bqg0,
    u16* __restrict__ wTall, float* __restrict__ bcatall)
{
    const int t = threadIdx.x;
    const int bid = blockIdx.x;
    if (bid >= 6480) {                        // bias concat: 216 blocks
        int i = (bid - 6480) * 256 + t;       // [0, 55296) = 12*4608
        int l = i / 4608, j = i - l * 4608;
        float v;
        if (j < 768)       v = bq0[l * 768 + j];
        else if (j < 1536) v = bk0[l * 768 + j - 768];
        else if (j < 2304) v = bv0[l * 768 + j - 1536];
        else if (j < 3072) v = bkg0[l * 768 + j - 2304];
        else if (j < 3840) v = bvg0[l * 768 + j - 3072];
        else               v = bqg0[l * 768 + j - 3840];
        bcatall[(size_t)l * 4608 + j] = v;
        return;
    }

    const int l = bid / 540, b = bid - l * 540;
    const size_t sqo = (size_t)l * 589824;
    const size_t sff = (size_t)l * 2359296;
    u16* wq = wTall + (size_t)l * 8847360;
    const float* src; u16* dst; int K, N, kt, ns;
    if (b < 216) {
        int m = b / 36, s = b - m * 36;
        src = ((m == 0) ? Wq0 : (m == 1) ? Wk0 : (m == 2) ? Wv0 :
               (m == 3) ? Wkg0 : (m == 4) ? Wvg0 : Wqg0) + sqo;
        dst = wq + (size_t)m * 589824;
        K = 768; N = 768; kt = s / 3; ns = s - kt * 3;
    } else if (b < 252) {
        int s = b - 216; src = Wo0 + sqo; dst = wq + 3538944;
        K = 768; N = 768; kt = s / 3; ns = s - kt * 3;
    } else if (b < 396) {
        int s = b - 252; src = W10 + sff; dst = wq + 4128768;
        K = 768; N = 3072; kt = s / 12; ns = s - kt * 12;
    } else {
        int s = b - 396; src = W20 + sff; dst = wq + 6488064;
        K = 3072; N = 768; kt = s / 3; ns = s - kt * 3;
    }
    const int k0 = kt * 64, n0b = ns * 256;

    __shared__ float tb[64][65];              // 65-stride: ~2-way banks
    const int r = t >> 4, c4 = (t & 15) * 4;
    const float* srow = src + (size_t)k0 * N + n0b;
    floatx4 rg[4];
    #pragma unroll
    for (int j = 0; j < 4; j++)
        rg[j] = __builtin_nontemporal_load(
            (const floatx4*)&srow[(size_t)(r + 16 * j) * N + c4]);

    #pragma unroll
    for (int s4 = 0; s4 < 4; ++s4) {
        #pragma unroll
        for (int j = 0; j < 4; j++) {         // write transposed into LDS
            int kk = r + 16 * j;
            #pragma unroll
            for (int i = 0; i < 4; i++) tb[c4 + i][kk] = rg[j][i];
        }
        __syncthreads();
        if (s4 < 3) {                          // prefetch next subtile -> regs
            #pragma unroll
            for (int j = 0; j < 4; j++)
                rg[j] = __builtin_nontemporal_load(
                    (const floatx4*)&srow[(size_t)(r + 16 * j) * N + (s4 + 1) * 64 + c4]);
        }
        int n0 = n0b + s4 * 64;
        #pragma unroll
        for (int j = 0; j < 4; j++) {         // cvt + coalesced u16x4 store
            int n = r + 16 * j;
            u16x4 o;
            #pragma unroll
            for (int i = 0; i < 4; i++) o[i] = f2h(tb[n][c4 + i]);
            __builtin_nontemporal_store(o, (u16x4*)&dst[(size_t)(n0 + n) * K + k0 + c4]);
        }
        if (s4 < 3) __syncthreads();          // reads done before next write
    }
}

// ---------------------------------------------------------------------------
// fp16 MFMA GEMM, BK=64 (global_load_lds staging, m97 pattern).
// - XCD-bijective swizzle on the flattened (x,y) grid (gridDim.x == 32).
// - SKIPQG: qg N-tiles (by>=30) only needed where bm%512==0.
// - WVT (proj only): v-column tiles write ONLY vTg (qkvg v-region is dead);
//   qg tiles store only GPOS rows ((r0+r)%512==0).
// - SPLITB: blockIdx.z = K-split (K arg = per-slice K); per-z fp16 slab via
//   Cb; bias only z==0. Otherwise WF->fp32 Cf / WB->fp16 Cb.
// ---------------------------------------------------------------------------
template <int ACT, int WF, int WB, int SKIPQG, int WVT, int SPLITB>
__global__ __launch_bounds__(256, 3) void gemm_k(
    const u16* __restrict__ A, const u16* __restrict__ Bt,
    const float* __restrict__ bias,
    float* __restrict__ Cf, u16* __restrict__ Cb, u16* __restrict__ vTg,
    int N, int K, int lda, int ldb)
{
    // XCD-bijective swizzle (nwg % 8 == 0 at every call site)
    int lin = blockIdx.y * 32 + blockIdx.x;
    int qq = gridDim.y << 2;                   // nwg/8 = 32*gy/8
    int wg = (lin & 7) * qq + (lin >> 3);
    int bx = wg & 31, by = wg >> 5;
    if (SKIPQG && by >= 30 && (bx & 3) != 0) return;
    int bm = bx * 128, bn = by * 128;
    const int zoff = SPLITB ? blockIdx.z : 0;
    const u16* Ab = A + (size_t)zoff * K;
    const u16* Bb = Bt + (size_t)zoff * K;
    u16* Csl = SPLITB ? Cb + (size_t)zoff * S_LEN * N : (u16*)nullptr;

    __shared__ __align__(16) u16 As[128][64];
    __shared__ __align__(16) u16 Bs[128][64];
    int t = threadIdx.x, lane = t & 63, wv = t >> 6;
    int wm = (wv >> 1) * 64, wn = (wv & 1) * 64;
    int srow = t >> 3, scol = (t & 7) * 8;     // staging: 32 rows/chunk x 64 cols
    int fr = lane & 15, fo = (lane >> 4) * 8;  // fragment row / k-offset

    floatx4 acc[4][4];
    #pragma unroll
    for (int i = 0; i < 4; i++)
        #pragma unroll
        for (int j = 0; j < 4; j++) acc[i][j] = (floatx4){0.f, 0.f, 0.f, 0.f};

    const int nk = K >> 6;
    for (int kt = 0; kt < nk; ++kt) {
        const u16* ag = Ab + (size_t)(bm + srow) * lda + kt * 64 + scol;
        const u16* bg = Bb + (size_t)(bn + srow) * ldb + kt * 64 + scol;
        #pragma unroll
        for (int c = 0; c < 4; ++c) {
            GLDS16(ag + (size_t)(32 * c) * lda, &As[srow + 32 * c][scol]);
            GLDS16(bg + (size_t)(32 * c) * ldb, &Bs[srow + 32 * c][scol]);
        }
        __syncthreads();
        #pragma unroll
        for (int ks = 0; ks < 2; ++ks) {
            halfx8 af[4], bfr[4];
            #pragma unroll
            for (int i = 0; i < 4; i++) af[i]  = *(const halfx8*)&As[wm + i * 16 + fr][ks * 32 + fo];
            #pragma unroll
            for (int i = 0; i < 4; i++) bfr[i] = *(const halfx8*)&Bs[wn + i * 16 + fr][ks * 32 + fo];
            #pragma unroll
            for (int i = 0; i < 4; i++)
                #pragma unroll
                for (int j = 0; j < 4; j++)
                    acc[i][j] = __builtin_amdgcn_mfma_f32_16x16x32_f16(af[i], bfr[j], acc[i][j], 0, 0, 0);
        }
        __syncthreads();
    }

    int dr = (lane >> 4) * 4, dc = lane & 15;
    #pragma unroll
    for (int i = 0; i < 4; i++) {
        #pragma unroll
        for (int j = 0; j < 4; j++) {
            int r0 = bm + wm + i * 16 + dr;
            int cc = bn + wn + j * 16 + dc;
            float bsv = (!SPLITB || blockIdx.z == 0) ? bias[cc] : 0.f;
            u16x4 tv;
            #pragma unroll
            for (int r = 0; r < 4; r++) {
                float v = acc[i][j][r] + bsv;
                if (ACT == 1) v = gelu_f(v);
                if (SPLITB) {
                    Csl[(size_t)(r0 + r) * N + cc] = f2h(v);
                } else {
                    if (WF) Cf[(size_t)(r0 + r) * N + cc] = v;
                    if (WB) {
                        u16 b = f2h(v);
                        tv[r] = b;
                        bool wr = true;
                        if (WVT) {
                            if (cc >= 1536 && cc < 2304) wr = false;   // dead v region
                            else if (cc >= 3840 && ((r0 + r) & 511) != 0) wr = false; // qg non-GPOS
                        }
                        if (wr) Cb[(size_t)(r0 + r) * N + cc] = b;
                    }
                }
            }
            if (WVT && cc >= 1536 && cc < 2304)
                *(u16x4*)&vTg[(size_t)(cc - 1536) * 4096 + r0] = tv;
        }
    }
}

// ---------------------------------------------------------------------------
// MFMA local banded attention (fp16) + joint softmax with 8 global CLS keys,
// plus fused global-attention merge (blocks with qb%8==0 own GPOS row qb*64;
// gpart ran as the PRIOR kernel -> partials visible, no device fences).
// grid (64 q-tiles, 12 heads) with XCD swizzle. T14 reg-prefetch staging.
// T5: setprio(1) around MFMA clusters (independent blocks at staggered
// phases per CU; scheduler favors MFMA-phase waves).
// ---------------------------------------------------------------------------
__global__ __launch_bounds__(256) void attn_local_k(
    const u16* __restrict__ qkvg, const u16* __restrict__ vTg, u16* __restrict__ aob,
    const float* __restrict__ pacc, const float* __restrict__ pm,
    const float* __restrict__ pl)
{
    int lin = blockIdx.y * 64 + blockIdx.x;   // nwg = 768
    int wg = (lin & 7) * 96 + (lin >> 3);
    const int qb = wg & 63, hh = wg >> 6;
    const int t = threadIdx.x, lane = t & 63, w = t >> 6;
    const int g = lane >> 4, qi = lane & 15;
    __shared__ __align__(16) u16 ks[64][72];
    __shared__ __align__(16) u16 vt[64][72];
    __shared__ __align__(16) u16 pbuf[4][16][40];

    const int q0w = qb * 64 + w * 16;
    const int sq = q0w + qi;                 // softmax-column query (per lane)

    halfx8 qf0, qf1;                          // Q B-operand frags (2 k-steps)
    {
        const u16* qp = qkvg + (size_t)(q0w + qi) * QKVG_N + hh * 64 + g * 8;
        qf0 = *(const halfx8*)qp;
        qf1 = *(const halfx8*)(qp + 32);
    }

    floatx4 acc[4];
    #pragma unroll
    for (int i = 0; i < 4; i++) acc[i] = (floatx4){0.f, 0.f, 0.f, 0.f};
    float mrun = -1e30f, lrun = 0.f;

    // local tile range (kbase = (qb + tile - 5)*64 in [0, 4032])
    int tlo = 5 - qb; if (tlo < 1) tlo = 1;
    int thi = 68 - qb; if (thi > 9) thi = 9;

    // per-thread staging coords: rows rs / rs+32, cols cs..cs+7
    const int rs = t >> 3, cs = (t & 7) * 8;
    uintx4 kr0, kr1, vr0, vr1;

    // ---- tile 0: stage 8 global CLS keys ----
    // zero only the consumed junk region vt[*][0..32) (P=0 x NaN guard)
    {
        int r0 = t >> 2, c0 = (t & 3) * 8;    // 256 threads cover 64x32
        *(uintx4*)&vt[r0][c0] = (uintx4){0, 0, 0, 0};
    }
    __syncthreads();
    if (t < 64) {
        int gg = t >> 3, d0 = (t & 7) * 8;
        *(uintx4*)&ks[gg][d0] =
            *(const uintx4*)(qkvg + (size_t)(gg * 512) * QKVG_N + 768 + hh * 64 + d0);
    }
    for (int e = t; e < 512; e += 256) {
        int d = e >> 3, gg = e & 7;
        vt[d][gg] = vTg[(size_t)(hh * 64 + d) * 4096 + gg * 512];
    }
    __syncthreads();

    // prefetch first local tile (loads overlap tile-0 compute below)
    {
        const int kb = (qb + tlo - 5) * 64;
        const u16* kp = qkvg + (size_t)(kb + rs) * QKVG_N + 768 + hh * 64 + cs;
        kr0 = *(const uintx4*)kp;
        kr1 = *(const uintx4*)(kp + (size_t)32 * QKVG_N);
        const u16* vp = vTg + (size_t)(hh * 64 + rs) * 4096 + kb + cs;
        vr0 = *(const uintx4*)vp;
        vr1 = *(const uintx4*)(vp + (size_t)32 * 4096);
    }

    // ---- tile 0 compute (kg2 = 0 only; keys kl<8 valid) ----
    {
        floatx4 sf0;
        {
            halfx8 ka0 = *(const halfx8*)&ks[qi][g * 8];
            halfx8 ka1 = *(const halfx8*)&ks[qi][32 + g * 8];
            floatx4 z = (floatx4){0.f, 0.f, 0.f, 0.f};
            __builtin_amdgcn_s_setprio(1);
            z = __builtin_amdgcn_mfma_f32_16x16x32_f16(ka0, qf0, z, 0, 0, 0);
            sf0 = __builtin_amdgcn_mfma_f32_16x16x32_f16(ka1, qf1, z, 0, 0, 0);
            __builtin_amdgcn_s_setprio(0);
        }
        float p8[8];
        float mloc = -1e30f;
        #pragma unroll
        for (int r = 0; r < 4; ++r) {
            int kl = g * 4 + r;
            float sc = (kl < 8) ? sf0[r] * 0.125f : -1e30f;
            p8[r] = sc;
            p8[4 + r] = -1e30f;
            mloc = fmaxf(mloc, sc);
        }
        mloc = fmaxf(mloc, __shfl_xor(mloc, 16));
        mloc = fmaxf(mloc, __shfl_xor(mloc, 32));
        float mnew = fmaxf(mrun, mloc);
        float alpha = __expf(mrun - mnew);
        mrun = mnew;
        float ls = 0.f;
        #pragma unroll
        for (int i = 0; i < 8; ++i) { float p = __expf(p8[i] - mnew); p8[i] = p; ls += p; }
        ls += __shfl_xor(ls, 16);
        ls += __shfl_xor(ls, 32);
        lrun = lrun * alpha + ls;
        u16x4 w0, w1;
        #pragma unroll
        for (int r = 0; r < 4; ++r) { w0[r] = f2h(p8[r]); w1[r] = f2h(p8[4 + r]); }
        *(u16x4*)&pbuf[w][qi][g * 4] = w0;
        *(u16x4*)&pbuf[w][qi][16 + g * 4] = w1;
        float al[4];
        #pragma unroll
        for (int r = 0; r < 4; ++r) al[r] = __shfl(alpha, g * 4 + r);
        #pragma unroll
        for (int dt = 0; dt < 4; ++dt)
            #pragma unroll
            for (int r = 0; r < 4; ++r) acc[dt][r] *= al[r];
        halfx8 pf = *(const halfx8*)&pbuf[w][qi][g * 8];
        __builtin_amdgcn_s_setprio(1);
        #pragma unroll
        for (int dt = 0; dt < 4; ++dt) {
            halfx8 vb = *(const halfx8*)&vt[dt * 16 + qi][g * 8];
            acc[dt] = __builtin_amdgcn_mfma_f32_16x16x32_f16(pf, vb, acc[dt], 0, 0, 0);
        }
        __builtin_amdgcn_s_setprio(0);
    }

    // ---- local tiles ----
    for (int tile = tlo; tile <= thi; ++tile) {
        const int kbase = (qb + tile - 5) * 64;
        __syncthreads();                       // prev compute done reading LDS
        *(uintx4*)&ks[rs][cs] = kr0;
        *(uintx4*)&ks[rs + 32][cs] = kr1;
        *(uintx4*)&vt[rs][cs] = vr0;
        *(uintx4*)&vt[rs + 32][cs] = vr1;
        __syncthreads();                       // LDS published
        if (tile < thi) {                      // prefetch next tile -> regs
            const int kb = kbase + 64;
            const u16* kp = qkvg + (size_t)(kb + rs) * QKVG_N + 768 + hh * 64 + cs;
            kr0 = *(const uintx4*)kp;
            kr1 = *(const uintx4*)(kp + (size_t)32 * QKVG_N);
            const u16* vp = vTg + (size_t)(hh * 64 + rs) * 4096 + kb + cs;
            vr0 = *(const uintx4*)vp;
            vr1 = *(const uintx4*)(vp + (size_t)32 * 4096);
        }
        const bool edge = (tile == 1) | (tile == 9);
        #pragma unroll
        for (int kg2 = 0; kg2 < 2; ++kg2) {
            floatx4 sf[2];
            __builtin_amdgcn_s_setprio(1);
            {
                halfx8 ka0 = *(const halfx8*)&ks[kg2 * 32 + qi][g * 8];
                halfx8 ka1 = *(const halfx8*)&ks[kg2 * 32 + qi][32 + g * 8];
                floatx4 z = (floatx4){0.f, 0.f, 0.f, 0.f};
                z = __builtin_amdgcn_mfma_f32_16x16x32_f16(ka0, qf0, z, 0, 0, 0);
                sf[0] = __builtin_amdgcn_mfma_f32_16x16x32_f16(ka1, qf1, z, 0, 0, 0);
            }
            {
                halfx8 kb0 = *(const halfx8*)&ks[kg2 * 32 + 16 + qi][g * 8];
                halfx8 kb1 = *(const halfx8*)&ks[kg2 * 32 + 16 + qi][32 + g * 8];
                floatx4 z = (floatx4){0.f, 0.f, 0.f, 0.f};
                z = __builtin_amdgcn_mfma_f32_16x16x32_f16(kb0, qf0, z, 0, 0, 0);
                sf[1] = __builtin_amdgcn_mfma_f32_16x16x32_f16(kb1, qf1, z, 0, 0, 0);
            }
            __builtin_amdgcn_s_setprio(0);
            float p8[8];
            float mloc = -1e30f;
            #pragma unroll
            for (int f = 0; f < 2; ++f)
                #pragma unroll
                for (int r = 0; r < 4; ++r) {
                    int kl = kg2 * 32 + f * 16 + g * 4 + r;
                    float sc = sf[f][r] * 0.125f;
                    if (edge) {
                        int dd = kbase + kl - sq;
                        if (dd > 256 || dd < -256) sc = -1e30f;
                    }
                    p8[f * 4 + r] = sc;
                    mloc = fmaxf(mloc, sc);
                }
            mloc = fmaxf(mloc, __shfl_xor(mloc, 16));
            mloc = fmaxf(mloc, __shfl_xor(mloc, 32));
            float mnew = fmaxf(mrun, mloc);
            float alpha = __expf(mrun - mnew);
            mrun = mnew;
            float ls = 0.f;
            #pragma unroll
            for (int i = 0; i < 8; ++i) { float p = __expf(p8[i] - mnew); p8[i] = p; ls += p; }
            ls += __shfl_xor(ls, 16);
            ls += __shfl_xor(ls, 32);
            lrun = lrun * alpha + ls;
            u16x4 w0, w1;
            #pragma unroll
            for (int r = 0; r < 4; ++r) { w0[r] = f2h(p8[r]); w1[r] = f2h(p8[4 + r]); }
            *(u16x4*)&pbuf[w][qi][g * 4] = w0;
            *(u16x4*)&pbuf[w][qi][16 + g * 4] = w1;
            float al[4];
            #pragma unroll
            for (int r = 0; r < 4; ++r) al[r] = __shfl(alpha, g * 4 + r);
            #pragma unroll
            for (int dt = 0; dt < 4; ++dt)
                #pragma unroll
                for (int r = 0; r < 4; ++r) acc[dt][r] *= al[r];
            halfx8 pf = *(const halfx8*)&pbuf[w][qi][g * 8];
            __builtin_amdgcn_s_setprio(1);
            #pragma unroll
            for (int dt = 0; dt < 4; ++dt) {
                halfx8 vb = *(const halfx8*)&vt[dt * 16 + qi][kg2 * 32 + g * 8];
                acc[dt] = __builtin_amdgcn_mfma_f32_16x16x32_f16(pf, vb, acc[dt], 0, 0, 0);
            }
            __builtin_amdgcn_s_setprio(0);
        }
    }

    float inv = 1.f / lrun;
    float li[4];
    #pragma unroll
    for (int r = 0; r < 4; ++r) li[r] = __shfl(inv, g * 4 + r);
    #pragma unroll
    for (int dt = 0; dt < 4; ++dt)
        #pragma unroll
        for (int r = 0; r < 4; ++r) {
            int s = q0w + g * 4 + r;
            aob[(size_t)s * 768 + hh * 64 + dt * 16 + qi] = f2h(acc[dt][r] * li[r]);
        }

    // ---- fused global-attention merge (blocks owning GPOS row qb*64) ----
    if ((qb & 7) == 0) {
        __syncthreads();                       // this block's aob stores drained
        if (t < 64) {
            int gq = qb >> 3;                  // GPOS row = gq*512 = qb*64
            float M = -1e30f;
            #pragma unroll 4
            for (int c = 0; c < 32; ++c)
                M = fmaxf(M, pm[((size_t)hh * 32 + c) * 8 + gq]);
            float L = 0.f, o = 0.f;
            #pragma unroll 4
            for (int c = 0; c < 32; ++c) {
                float wz = __expf(pm[((size_t)hh * 32 + c) * 8 + gq] - M);
                L += pl[((size_t)hh * 32 + c) * 8 + gq] * wz;
                o += wz * pacc[(((size_t)hh * 32 + c) * 8 + gq) * 64 + t];
            }
            aob[(size_t)(gq * 512) * 768 + hh * 64 + t] = f2h(o / L);
        }
    }
}

// ---------------------------------------------------------------------------
// Embedding + LN, vectorized: 192 threads x float4. fp16 hidden state.
// ---------------------------------------------------------------------------
__global__ __launch_bounds__(192) void embed_ln_k(
    const int* __restrict__ x, const float* __restrict__ wemb, const float* __restrict__ pemb,
    const float* __restrict__ gs, const float* __restrict__ gb,
    u16* __restrict__ hh)
{
    int s = blockIdx.x, t = threadIdx.x;
    int w = s >> 9, p = s & 511;
    int id = (p == 0) ? 0 : x[w * 511 + p - 1];
    size_t off = (size_t)s * 768 + t * 4;
    floatx4 a = *(const floatx4*)(wemb + (size_t)id * 768 + t * 4);
    floatx4 b = *(const floatx4*)(pemb + off);
    floatx4 v;
    #pragma unroll
    for (int i = 0; i < 4; i++) v[i] = a[i] + b[i];
    float sum = v[0] + v[1] + v[2] + v[3];
    float sq = v[0] * v[0] + v[1] * v[1] + v[2] * v[2] + v[3] * v[3];
    #pragma unroll
    for (int o = 32; o > 0; o >>= 1) {
        sum += __shfl_down(sum, o); sq += __shfl_down(sq, o);
    }
    __shared__ float rs_[3], rq_[3];
    if ((t & 63) == 0) { rs_[t >> 6] = sum; rq_[t >> 6] = sq; }
    __syncthreads();
    float S = rs_[0] + rs_[1] + rs_[2];
    float Q = rq_[0] + rq_[1] + rq_[2];
    float mean = S * (1.f / 768.f);
    float inv = rsqrtf(Q * (1.f / 768.f) - mean * mean + 1e-5f);
    floatx4 g4 = *(const floatx4*)(gs + t * 4);
    floatx4 b4 = *(const floatx4*)(gb + t * 4);
    u16x4 oh;
    #pragma unroll
    for (int i = 0; i < 4; i++) {
        float y = (v[i] - mean) * inv * g4[i] + b4[i];
        oh[i] = f2h(y);
    }
    *(u16x4*)(hh + off) = oh;
}

// oh = LN(xa + sum_z yh[z]): all fp16; xa in-place ok. 192 thr x float4.
__global__ __launch_bounds__(192) void ln_resid_k(
    const u16* __restrict__ xa, const u16* __restrict__ yh,
    const float* __restrict__ gs, const float* __restrict__ gb,
    u16* __restrict__ oh)
{
    int s = blockIdx.x, t = threadIdx.x;      // t in [0,192)
    size_t off = (size_t)s * 768 + t * 4;
    u16x4 xa4 = *(const u16x4*)(xa + off);
    floatx4 v;
    #pragma unroll
    for (int i = 0; i < 4; i++) v[i] = h2f(xa4[i]);
    #pragma unroll
    for (int z = 0; z < 4; z++) {
        u16x4 b = *(const u16x4*)(yh + (size_t)z * 4096 * 768 + off);
        #pragma unroll
        for (int i = 0; i < 4; i++) v[i] += h2f(b[i]);
    }
    float sum = v[0] + v[1] + v[2] + v[3];
    float sq = v[0] * v[0] + v[1] * v[1] + v[2] * v[2] + v[3] * v[3];
    #pragma unroll
    for (int o = 32; o > 0; o >>= 1) {
        sum += __shfl_down(sum, o); sq += __shfl_down(sq, o);
    }
    __shared__ float rs_[3], rq_[3];
    if ((t & 63) == 0) { rs_[t >> 6] = sum; rq_[t >> 6] = sq; }
    __syncthreads();
    float S = rs_[0] + rs_[1] + rs_[2];
    float Q = rq_[0] + rq_[1] + rq_[2];
    float mean = S * (1.f / 768.f);
    float inv = rsqrtf(Q * (1.f / 768.f) - mean * mean + 1e-5f);
    floatx4 g4 = *(const floatx4*)(gs + t * 4);
    floatx4 b4 = *(const floatx4*)(gb + t * 4);
    u16x4 ohh;
    #pragma unroll
    for (int i = 0; i < 4; i++) {
        float y = (v[i] - mean) * inv * g4[i] + b4[i];
        ohh[i] = f2h(y);
    }
    *(u16x4*)(oh + off) = ohh;
}

// ---------------------------------------------------------------------------
// Global-token attention, pass 1: split-K partials (fp16 inputs).
// grid (12 heads, 32 key-chunks of 128), 256 threads.
// ---------------------------------------------------------------------------
__global__ __launch_bounds__(256) void attn_gpart_k(
    const u16* __restrict__ qkvg,
    float* __restrict__ pacc, float* __restrict__ pm, float* __restrict__ pl)
{
    const int hh = blockIdx.x, ck = blockIdx.y;
    const int t = threadIdx.x;
    __shared__ float qs[8][64];
    __shared__ __align__(16) u16 ks[128][72];   // +8 pad: stage writes c-free
    __shared__ __align__(16) u16 vs[128][64];   // read d-major -> conflict-free
    __shared__ float sc[8][128];
    __shared__ float mred[8], lred[8];

    for (int i = t; i < 512; i += 256) {
        int g = i >> 6, d = i & 63;
        qs[g][d] = h2f(qkvg[(size_t)(g * 512) * QKVG_N + 3840 + hh * 64 + d]) * 0.125f;
    }
    const int s0 = ck * 128;
    for (int u = t; u < 1024; u += 256) {
        int r = u >> 3, c = u & 7;
        const u16* src = qkvg + (size_t)(s0 + r) * QKVG_N + hh * 64 + c * 8;
        *(uintx4*)&ks[r][c * 8] = *(const uintx4*)(src + 2304);
        *(uintx4*)&vs[r][c * 8] = *(const uintx4*)(src + 3072);
    }
    __syncthreads();

    // scores: thread (key = t&127) computes 4 queries (t>>7 selects 0-3 / 4-7)
    {
        int key = t & 127, q0 = (t >> 7) * 4;
        float a[4] = {0.f, 0.f, 0.f, 0.f};
        #pragma unroll
        for (int c = 0; c < 8; ++c) {
            uintx4 pk = *(const uintx4*)&ks[key][c * 8];
            const u16* uu = (const u16*)&pk;
            #pragma unroll
            for (int e = 0; e < 8; ++e) {
                float kv = h2f(uu[e]);
                #pragma unroll
                for (int q = 0; q < 4; ++q) a[q] += kv * qs[q0 + q][c * 8 + e];
            }
        }
        #pragma unroll
        for (int q = 0; q < 4; ++q) sc[q0 + q][key] = a[q];
    }
    __syncthreads();

    // chunk softmax: q = t>>5, 32 lanes/query, 4 keys each
    {
        int q = t >> 5, lq = t & 31;
        float m = -1e30f;
        #pragma unroll
        for (int i = 0; i < 4; ++i) m = fmaxf(m, sc[q][lq + i * 32]);
        #pragma unroll
        for (int o = 1; o < 32; o <<= 1) m = fmaxf(m, __shfl_xor(m, o));
        float ls = 0.f;
        #pragma unroll
        for (int i = 0; i < 4; ++i) {
            float p = __expf(sc[q][lq + i * 32] - m);
            sc[q][lq + i * 32] = p; ls += p;
        }
        #pragma unroll
        for (int o = 1; o < 32; o <<= 1) ls += __shfl_xor(ls, o);
        if (lq == 0) { mred[q] = m; lred[q] = ls; }
    }
    __syncthreads();

    // partial PV: thread (d = t&63, qb = t>>6) -> o[qb][d], o[qb+4][d]
    {
        int d = t & 63, qb = t >> 6;
        float a0 = 0.f, a1 = 0.f;
        #pragma unroll 4
        for (int s = 0; s < 128; ++s) {
            float v = h2f(vs[s][d]);
            a0 += sc[qb][s] * v;
            a1 += sc[qb + 4][s] * v;
        }
        float* pb = pacc + (((size_t)hh * 32 + ck) * 8) * 64;
        pb[qb * 64 + d] = a0;
        pb[(qb + 4) * 64 + d] = a1;
        if (t < 8) {
            pm[((size_t)hh * 32 + ck) * 8 + t] = mred[t];
            pl[((size_t)hh * 32 + ck) * 8 + t] = lred[t];
        }
    }
}

__global__ __launch_bounds__(128) void head_k(
    const u16* __restrict__ hh, const float* __restrict__ Wout,
    const float* __restrict__ bout, float* __restrict__ out)
{
    int g = blockIdx.x, n = threadIdx.x;
    __shared__ float hsh[768];
    for (int i = n; i < 768; i += 128) hsh[i] = h2f(hh[(size_t)(g * 512) * 768 + i]);
    __syncthreads();
    float a = 0.f;
    #pragma unroll 4
    for (int k = 0; k < 768; k++) a += hsh[k] * Wout[k * 128 + n];
    out[g * 128 + n] = a + bout[n];
}

// ---------------------------------------------------------------------------
extern "C" void kernel_launch(void* const* d_in, const int* in_sizes, int n_in,
                              void* d_out, int out_size, void* d_ws, size_t ws_size,
                              hipStream_t stream)
{
    (void)in_sizes; (void)n_in; (void)out_size; (void)ws_size;
    const int*   x    = (const int*)  d_in[0];
    const float* wemb = (const float*)d_in[1];
    const float* pemb = (const float*)d_in[2];
    const float* elns = (const float*)d_in[3];
    const float* elnb = (const float*)d_in[4];
    const float* Wq   = (const float*)d_in[5];
    const float* bq   = (const float*)d_in[6];
    const float* Wk   = (const float*)d_in[7];
    const float* bk   = (const float*)d_in[8];
    const float* Wv   = (const float*)d_in[9];
    const float* bv   = (const float*)d_in[10];
    const float* Wo   = (const float*)d_in[11];
    const float* bo   = (const float*)d_in[12];
    const float* Wqg  = (const float*)d_in[13];
    const float* bqg  = (const float*)d_in[14];
    const float* Wkg  = (const float*)d_in[15];
    const float* bkg  = (const float*)d_in[16];
    const float* Wvg  = (const float*)d_in[17];
    const float* bvg  = (const float*)d_in[18];
    const float* l1s  = (const float*)d_in[19];
    const float* l1b  = (const float*)d_in[20];
    const float* W1   = (const float*)d_in[21];
    const float* b1   = (const float*)d_in[22];
    const float* W2   = (const float*)d_in[23];
    const float* b2   = (const float*)d_in[24];
    const float* l2s  = (const float*)d_in[25];
    const float* l2b  = (const float*)d_in[26];
    const float* Wout = (const float*)d_in[27];
    const float* boutp= (const float*)d_in[28];

    char* W = (char*)d_ws;
    u16*   hh    = (u16*)  (W);                  // [4096][768]  fp16 hidden
    u16*   qkvg  = (u16*)  (W + 18874368);       // [4096][4608] fp16
    u16*   ff1b  = (u16*)  (W + 18874368);       // [4096][3072] fp16 (reuses
                                                 //  qkvg after attn is done)
    u16*   vTg   = (u16*)  (W + 56623104);       // [768][4096]  fp16
    u16*   aob   = (u16*)  (W + 62914560);       // [4096][768]  fp16
    u16*   yh    = (u16*)  (W + 69206016);       // [4][4096][768] fp16 slabs
    float* pacc  = (float*)(W + 119537664);      // [12][32][8][64] fp32
    float* pmw   = (float*)(W + 120324096);      // [12][32][8]     fp32
    float* plw   = (float*)(W + 120336384);      // [12][32][8]     fp32
    float* bcatall = (float*)(W + 120348672);    // [12][4608]      fp32
    u16*   wTall = (u16*)  (W + 120569856);      // [12] x 8847360 u16 (fp16)

    // All-layer weight prep (one launch, single-buffer LDS, NT streams)
    prep_weights_k<<<6696, 256, 0, stream>>>(
        Wq, Wk, Wv, Wkg, Wvg, Wqg, Wo, W1, W2,
        bq, bk, bv, bkg, bvg, bqg, wTall, bcatall);

    embed_ln_k<<<4096, 192, 0, stream>>>(x, wemb, pemb, elns, elnb, hh);

    for (int l = 0; l < NL; ++l) {
        u16* wTl      = wTall + (size_t)l * 8847360;
        u16* wqkvgT_l = wTl;
        u16* woT_l    = wTl + 3538944;
        u16* w1T_l    = woT_l + 589824;
        u16* w2T_l    = w1T_l + 2359296;
        float* bcat_l = bcatall + (size_t)l * 4608;
        const float* bo_l  = bo  + (size_t)l * 768;
        const float* b1_l  = b1  + (size_t)l * 3072;
        const float* b2_l  = b2  + (size_t)l * 768;
        const float* l1s_l = l1s + (size_t)l * 768;
        const float* l1b_l = l1b + (size_t)l * 768;
        const float* l2s_l = l2s + (size_t)l * 768;
        const float* l2b_l = l2b + (size_t)l * 768;

        // fused q/k/v/kg/vg/qg projection -> fp16 [4096][4608] (+ vTg fused,
        // dead v/qg-row writes skipped)
        gemm_k<0, 0, 1, 1, 1, 0><<<dim3(32, 36), 256, 0, stream>>>(
            hh, wqkvgT_l, bcat_l, (float*)nullptr, qkvg, vTg, QKVG_N, 768, 768, 768);

        // global-attention partials FIRST (kernel boundary -> visible to the
        // fused merge in attn_local)
        attn_gpart_k<<<dim3(12, 32), 256, 0, stream>>>(qkvg, pacc, pmw, plw);

        attn_local_k<<<dim3(64, 12), 256, 0, stream>>>(qkvg, vTg, aob, pacc, pmw, plw);

        // attention output proj, split-K x4 (K=768/4=192) -> fp16 slabs
        gemm_k<0, 0, 0, 0, 0, 1><<<dim3(32, 6, 4), 256, 0, stream>>>(
            aob, woT_l, bo_l, (float*)nullptr, yh, (u16*)nullptr, 768, 192, 768, 768);
        ln_resid_k<<<4096, 192, 0, stream>>>(hh, yh, l1s_l, l1b_l, hh);

        gemm_k<1, 0, 1, 0, 0, 0><<<dim3(32, 24), 256, 0, stream>>>(
            hh, w1T_l, b1_l, (float*)nullptr, ff1b, (u16*)nullptr, 3072, 768, 768, 768);
        // FFN down proj, split-K x4 (K=3072/4=768) -> fp16 slabs
        gemm_k<0, 0, 0, 0, 0, 1><<<dim3(32, 6, 4), 256, 0, stream>>>(
            ff1b, w2T_l, b2_l, (float*)nullptr, yh, (u16*)nullptr, 768, 768, 3072, 3072);
        ln_resid_k<<<4096, 192, 0, stream>>>(hh, yh, l2s_l, l2b_l, hh);
    }

    head_k<<<8, 128, 0, stream>>>(hh, Wout, boutp, (float*)d_out);
}

// Round 20
// 2461.336 us; speedup vs baseline: 1.0073x; 1.0073x over previous
//
#include <hip/hip_runtime.h>
#include <hip/hip_bf16.h>

// ---------------------------------------------------------------------------
// Longformer forward, MI355X. Round 21: occupancy fix for the proj GEMM —
// its ~1008 working blocks exceed 3-blocks/CU residency (768), forcing a
// ragged ~31%-fill tail wave. __launch_bounds__(256,4) via MINW template
// param (proj only) -> 1024 slots, single co-resident wave. setprio (null
// in R19) reverted. Base: R18 (2478.5 us best).
// Constants: B=1 NW=8 SEG=511 S=4096 W=256 C=16 H=12 D=64 DM=768 FF=3072 L=12
// ---------------------------------------------------------------------------

typedef unsigned short u16;
typedef __attribute__((ext_vector_type(4))) float floatx4;
typedef __attribute__((ext_vector_type(4))) unsigned int uintx4;
typedef __attribute__((ext_vector_type(8))) _Float16 halfx8;
typedef __attribute__((ext_vector_type(4))) u16 u16x4;

#define S_LEN 4096
#define QKVG_N 4608   // q(0) k(768) v(1536,DEAD) kg(2304) vg(3072) qg(3840)
#define NL 12

__device__ inline u16 f2h(float x) {
    union { _Float16 h; u16 u; } c; c.h = (_Float16)x; return c.u;
}
__device__ inline float h2f(u16 u) {
    union { _Float16 h; u16 u; } c; c.u = u; return (float)c.h;
}
__device__ inline float gelu_f(float x) {
    float x3 = x * x * x;
    return 0.5f * x * (1.0f + tanhf(0.7978845608028654f * (x + 0.044715f * x3)));
}

#define GLDS16(g, l)                                                              \
    __builtin_amdgcn_global_load_lds(                                             \
        (const __attribute__((address_space(1))) unsigned int*)(g),               \
        (__attribute__((address_space(3))) unsigned int*)(l), 16, 0, 0)

// ---------------------------------------------------------------------------
// Weight prep v5: fp32 [K][N] -> fp16 [N][K], all layers, one launch.
// Single [64][65] fp32 LDS; NT streams (3.7 TB/s, pattern-limited floor;
// 92% of compulsory-traffic roofline -> closed).
// ---------------------------------------------------------------------------
__global__ __launch_bounds__(256) void prep_weights_k(
    const float* __restrict__ Wq0, const float* __restrict__ Wk0, const float* __restrict__ Wv0,
    const float* __restrict__ Wkg0, const float* __restrict__ Wvg0, const float* __restrict__ Wqg0,
    const float* __restrict__ Wo0, const float* __restrict__ W10, const float* __restrict__ W20,
    const float* __restrict__ bq0, const float* __restrict__ bk0, const float* __restrict__ bv0,
    const float* __restrict__ bkg0, const float* __restrict__ bvg0, const float* __restrict__ bqg0,
    u16* __restrict__ wTall, float* __restrict__ bcatall)
{
    const int t = threadIdx.x;
    const int bid = blockIdx.x;
    if (bid >= 6480) {                        // bias concat: 216 blocks
        int i = (bid - 6480) * 256 + t;       // [0, 55296) = 12*4608
        int l = i / 4608, j = i - l * 4608;
        float v;
        if (j < 768)       v = bq0[l * 768 + j];
        else if (j < 1536) v = bk0[l * 768 + j - 768];
        else if (j < 2304) v = bv0[l * 768 + j - 1536];
        else if (j < 3072) v = bkg0[l * 768 + j - 2304];
        else if (j < 3840) v = bvg0[l * 768 + j - 3072];
        else               v = bqg0[l * 768 + j - 3840];
        bcatall[(size_t)l * 4608 + j] = v;
        return;
    }

    const int l = bid / 540, b = bid - l * 540;
    const size_t sqo = (size_t)l * 589824;
    const size_t sff = (size_t)l * 2359296;
    u16* wq = wTall + (size_t)l * 8847360;
    const float* src; u16* dst; int K, N, kt, ns;
    if (b < 216) {
        int m = b / 36, s = b - m * 36;
        src = ((m == 0) ? Wq0 : (m == 1) ? Wk0 : (m == 2) ? Wv0 :
               (m == 3) ? Wkg0 : (m == 4) ? Wvg0 : Wqg0) + sqo;
        dst = wq + (size_t)m * 589824;
        K = 768; N = 768; kt = s / 3; ns = s - kt * 3;
    } else if (b < 252) {
        int s = b - 216; src = Wo0 + sqo; dst = wq + 3538944;
        K = 768; N = 768; kt = s / 3; ns = s - kt * 3;
    } else if (b < 396) {
        int s = b - 252; src = W10 + sff; dst = wq + 4128768;
        K = 768; N = 3072; kt = s / 12; ns = s - kt * 12;
    } else {
        int s = b - 396; src = W20 + sff; dst = wq + 6488064;
        K = 3072; N = 768; kt = s / 3; ns = s - kt * 3;
    }
    const int k0 = kt * 64, n0b = ns * 256;

    __shared__ float tb[64][65];              // 65-stride: ~2-way banks
    const int r = t >> 4, c4 = (t & 15) * 4;
    const float* srow = src + (size_t)k0 * N + n0b;
    floatx4 rg[4];
    #pragma unroll
    for (int j = 0; j < 4; j++)
        rg[j] = __builtin_nontemporal_load(
            (const floatx4*)&srow[(size_t)(r + 16 * j) * N + c4]);

    #pragma unroll
    for (int s4 = 0; s4 < 4; ++s4) {
        #pragma unroll
        for (int j = 0; j < 4; j++) {         // write transposed into LDS
            int kk = r + 16 * j;
            #pragma unroll
            for (int i = 0; i < 4; i++) tb[c4 + i][kk] = rg[j][i];
        }
        __syncthreads();
        if (s4 < 3) {                          // prefetch next subtile -> regs
            #pragma unroll
            for (int j = 0; j < 4; j++)
                rg[j] = __builtin_nontemporal_load(
                    (const floatx4*)&srow[(size_t)(r + 16 * j) * N + (s4 + 1) * 64 + c4]);
        }
        int n0 = n0b + s4 * 64;
        #pragma unroll
        for (int j = 0; j < 4; j++) {         // cvt + coalesced u16x4 store
            int n = r + 16 * j;
            u16x4 o;
            #pragma unroll
            for (int i = 0; i < 4; i++) o[i] = f2h(tb[n][c4 + i]);
            __builtin_nontemporal_store(o, (u16x4*)&dst[(size_t)(n0 + n) * K + k0 + c4]);
        }
        if (s4 < 3) __syncthreads();          // reads done before next write
    }
}

// ---------------------------------------------------------------------------
// fp16 MFMA GEMM, BK=64 (global_load_lds staging, m97 pattern).
// - XCD-bijective swizzle on the flattened (x,y) grid (gridDim.x == 32).
// - SKIPQG: qg N-tiles (by>=30) only needed where bm%512==0.
// - WVT (proj only): v-column tiles write ONLY vTg (qkvg v-region is dead);
//   qg tiles store only GPOS rows ((r0+r)%512==0).
// - SPLITB: blockIdx.z = K-split (K arg = per-slice K); per-z fp16 slab via
//   Cb; bias only z==0. Otherwise WF->fp32 Cf / WB->fp16 Cb.
// - MINW: min blocks/CU (launch_bounds 2nd arg = waves/EU = blocks/CU at
//   256 thr). proj uses 4 (1008 working blocks > 768 slots at 3); others 3.
// ---------------------------------------------------------------------------
template <int ACT, int WF, int WB, int SKIPQG, int WVT, int SPLITB, int MINW>
__global__ __launch_bounds__(256, MINW) void gemm_k(
    const u16* __restrict__ A, const u16* __restrict__ Bt,
    const float* __restrict__ bias,
    float* __restrict__ Cf, u16* __restrict__ Cb, u16* __restrict__ vTg,
    int N, int K, int lda, int ldb)
{
    // XCD-bijective swizzle (nwg % 8 == 0 at every call site)
    int lin = blockIdx.y * 32 + blockIdx.x;
    int qq = gridDim.y << 2;                   // nwg/8 = 32*gy/8
    int wg = (lin & 7) * qq + (lin >> 3);
    int bx = wg & 31, by = wg >> 5;
    if (SKIPQG && by >= 30 && (bx & 3) != 0) return;
    int bm = bx * 128, bn = by * 128;
    const int zoff = SPLITB ? blockIdx.z : 0;
    const u16* Ab = A + (size_t)zoff * K;
    const u16* Bb = Bt + (size_t)zoff * K;
    u16* Csl = SPLITB ? Cb + (size_t)zoff * S_LEN * N : (u16*)nullptr;

    __shared__ __align__(16) u16 As[128][64];
    __shared__ __align__(16) u16 Bs[128][64];
    int t = threadIdx.x, lane = t & 63, wv = t >> 6;
    int wm = (wv >> 1) * 64, wn = (wv & 1) * 64;
    int srow = t >> 3, scol = (t & 7) * 8;     // staging: 32 rows/chunk x 64 cols
    int fr = lane & 15, fo = (lane >> 4) * 8;  // fragment row / k-offset

    floatx4 acc[4][4];
    #pragma unroll
    for (int i = 0; i < 4; i++)
        #pragma unroll
        for (int j = 0; j < 4; j++) acc[i][j] = (floatx4){0.f, 0.f, 0.f, 0.f};

    const int nk = K >> 6;
    for (int kt = 0; kt < nk; ++kt) {
        const u16* ag = Ab + (size_t)(bm + srow) * lda + kt * 64 + scol;
        const u16* bg = Bb + (size_t)(bn + srow) * ldb + kt * 64 + scol;
        #pragma unroll
        for (int c = 0; c < 4; ++c) {
            GLDS16(ag + (size_t)(32 * c) * lda, &As[srow + 32 * c][scol]);
            GLDS16(bg + (size_t)(32 * c) * ldb, &Bs[srow + 32 * c][scol]);
        }
        __syncthreads();
        #pragma unroll
        for (int ks = 0; ks < 2; ++ks) {
            halfx8 af[4], bfr[4];
            #pragma unroll
            for (int i = 0; i < 4; i++) af[i]  = *(const halfx8*)&As[wm + i * 16 + fr][ks * 32 + fo];
            #pragma unroll
            for (int i = 0; i < 4; i++) bfr[i] = *(const halfx8*)&Bs[wn + i * 16 + fr][ks * 32 + fo];
            #pragma unroll
            for (int i = 0; i < 4; i++)
                #pragma unroll
                for (int j = 0; j < 4; j++)
                    acc[i][j] = __builtin_amdgcn_mfma_f32_16x16x32_f16(af[i], bfr[j], acc[i][j], 0, 0, 0);
        }
        __syncthreads();
    }

    int dr = (lane >> 4) * 4, dc = lane & 15;
    #pragma unroll
    for (int i = 0; i < 4; i++) {
        #pragma unroll
        for (int j = 0; j < 4; j++) {
            int r0 = bm + wm + i * 16 + dr;
            int cc = bn + wn + j * 16 + dc;
            float bsv = (!SPLITB || blockIdx.z == 0) ? bias[cc] : 0.f;
            u16x4 tv;
            #pragma unroll
            for (int r = 0; r < 4; r++) {
                float v = acc[i][j][r] + bsv;
                if (ACT == 1) v = gelu_f(v);
                if (SPLITB) {
                    Csl[(size_t)(r0 + r) * N + cc] = f2h(v);
                } else {
                    if (WF) Cf[(size_t)(r0 + r) * N + cc] = v;
                    if (WB) {
                        u16 b = f2h(v);
                        tv[r] = b;
                        bool wr = true;
                        if (WVT) {
                            if (cc >= 1536 && cc < 2304) wr = false;   // dead v region
                            else if (cc >= 3840 && ((r0 + r) & 511) != 0) wr = false; // qg non-GPOS
                        }
                        if (wr) Cb[(size_t)(r0 + r) * N + cc] = b;
                    }
                }
            }
            if (WVT && cc >= 1536 && cc < 2304)
                *(u16x4*)&vTg[(size_t)(cc - 1536) * 4096 + r0] = tv;
        }
    }
}

// ---------------------------------------------------------------------------
// MFMA local banded attention (fp16) + joint softmax with 8 global CLS keys,
// plus fused global-attention merge (blocks with qb%8==0 own GPOS row qb*64;
// gpart ran as the PRIOR kernel -> partials visible, no device fences).
// grid (64 q-tiles, 12 heads) with XCD swizzle. T14 reg-prefetch staging.
// ---------------------------------------------------------------------------
__global__ __launch_bounds__(256) void attn_local_k(
    const u16* __restrict__ qkvg, const u16* __restrict__ vTg, u16* __restrict__ aob,
    const float* __restrict__ pacc, const float* __restrict__ pm,
    const float* __restrict__ pl)
{
    int lin = blockIdx.y * 64 + blockIdx.x;   // nwg = 768
    int wg = (lin & 7) * 96 + (lin >> 3);
    const int qb = wg & 63, hh = wg >> 6;
    const int t = threadIdx.x, lane = t & 63, w = t >> 6;
    const int g = lane >> 4, qi = lane & 15;
    __shared__ __align__(16) u16 ks[64][72];
    __shared__ __align__(16) u16 vt[64][72];
    __shared__ __align__(16) u16 pbuf[4][16][40];

    const int q0w = qb * 64 + w * 16;
    const int sq = q0w + qi;                 // softmax-column query (per lane)

    halfx8 qf0, qf1;                          // Q B-operand frags (2 k-steps)
    {
        const u16* qp = qkvg + (size_t)(q0w + qi) * QKVG_N + hh * 64 + g * 8;
        qf0 = *(const halfx8*)qp;
        qf1 = *(const halfx8*)(qp + 32);
    }

    floatx4 acc[4];
    #pragma unroll
    for (int i = 0; i < 4; i++) acc[i] = (floatx4){0.f, 0.f, 0.f, 0.f};
    float mrun = -1e30f, lrun = 0.f;

    // local tile range (kbase = (qb + tile - 5)*64 in [0, 4032])
    int tlo = 5 - qb; if (tlo < 1) tlo = 1;
    int thi = 68 - qb; if (thi > 9) thi = 9;

    // per-thread staging coords: rows rs / rs+32, cols cs..cs+7
    const int rs = t >> 3, cs = (t & 7) * 8;
    uintx4 kr0, kr1, vr0, vr1;

    // ---- tile 0: stage 8 global CLS keys ----
    // zero only the consumed junk region vt[*][0..32) (P=0 x NaN guard)
    {
        int r0 = t >> 2, c0 = (t & 3) * 8;    // 256 threads cover 64x32
        *(uintx4*)&vt[r0][c0] = (uintx4){0, 0, 0, 0};
    }
    __syncthreads();
    if (t < 64) {
        int gg = t >> 3, d0 = (t & 7) * 8;
        *(uintx4*)&ks[gg][d0] =
            *(const uintx4*)(qkvg + (size_t)(gg * 512) * QKVG_N + 768 + hh * 64 + d0);
    }
    for (int e = t; e < 512; e += 256) {
        int d = e >> 3, gg = e & 7;
        vt[d][gg] = vTg[(size_t)(hh * 64 + d) * 4096 + gg * 512];
    }
    __syncthreads();

    // prefetch first local tile (loads overlap tile-0 compute below)
    {
        const int kb = (qb + tlo - 5) * 64;
        const u16* kp = qkvg + (size_t)(kb + rs) * QKVG_N + 768 + hh * 64 + cs;
        kr0 = *(const uintx4*)kp;
        kr1 = *(const uintx4*)(kp + (size_t)32 * QKVG_N);
        const u16* vp = vTg + (size_t)(hh * 64 + rs) * 4096 + kb + cs;
        vr0 = *(const uintx4*)vp;
        vr1 = *(const uintx4*)(vp + (size_t)32 * 4096);
    }

    // ---- tile 0 compute (kg2 = 0 only; keys kl<8 valid) ----
    {
        floatx4 sf0;
        {
            halfx8 ka0 = *(const halfx8*)&ks[qi][g * 8];
            halfx8 ka1 = *(const halfx8*)&ks[qi][32 + g * 8];
            floatx4 z = (floatx4){0.f, 0.f, 0.f, 0.f};
            z = __builtin_amdgcn_mfma_f32_16x16x32_f16(ka0, qf0, z, 0, 0, 0);
            sf0 = __builtin_amdgcn_mfma_f32_16x16x32_f16(ka1, qf1, z, 0, 0, 0);
        }
        float p8[8];
        float mloc = -1e30f;
        #pragma unroll
        for (int r = 0; r < 4; ++r) {
            int kl = g * 4 + r;
            float sc = (kl < 8) ? sf0[r] * 0.125f : -1e30f;
            p8[r] = sc;
            p8[4 + r] = -1e30f;
            mloc = fmaxf(mloc, sc);
        }
        mloc = fmaxf(mloc, __shfl_xor(mloc, 16));
        mloc = fmaxf(mloc, __shfl_xor(mloc, 32));
        float mnew = fmaxf(mrun, mloc);
        float alpha = __expf(mrun - mnew);
        mrun = mnew;
        float ls = 0.f;
        #pragma unroll
        for (int i = 0; i < 8; ++i) { float p = __expf(p8[i] - mnew); p8[i] = p; ls += p; }
        ls += __shfl_xor(ls, 16);
        ls += __shfl_xor(ls, 32);
        lrun = lrun * alpha + ls;
        u16x4 w0, w1;
        #pragma unroll
        for (int r = 0; r < 4; ++r) { w0[r] = f2h(p8[r]); w1[r] = f2h(p8[4 + r]); }
        *(u16x4*)&pbuf[w][qi][g * 4] = w0;
        *(u16x4*)&pbuf[w][qi][16 + g * 4] = w1;
        float al[4];
        #pragma unroll
        for (int r = 0; r < 4; ++r) al[r] = __shfl(alpha, g * 4 + r);
        #pragma unroll
        for (int dt = 0; dt < 4; ++dt)
            #pragma unroll
            for (int r = 0; r < 4; ++r) acc[dt][r] *= al[r];
        halfx8 pf = *(const halfx8*)&pbuf[w][qi][g * 8];
        #pragma unroll
        for (int dt = 0; dt < 4; ++dt) {
            halfx8 vb = *(const halfx8*)&vt[dt * 16 + qi][g * 8];
            acc[dt] = __builtin_amdgcn_mfma_f32_16x16x32_f16(pf, vb, acc[dt], 0, 0, 0);
        }
    }

    // ---- local tiles ----
    for (int tile = tlo; tile <= thi; ++tile) {
        const int kbase = (qb + tile - 5) * 64;
        __syncthreads();                       // prev compute done reading LDS
        *(uintx4*)&ks[rs][cs] = kr0;
        *(uintx4*)&ks[rs + 32][cs] = kr1;
        *(uintx4*)&vt[rs][cs] = vr0;
        *(uintx4*)&vt[rs + 32][cs] = vr1;
        __syncthreads();                       // LDS published
        if (tile < thi) {                      // prefetch next tile -> regs
            const int kb = kbase + 64;
            const u16* kp = qkvg + (size_t)(kb + rs) * QKVG_N + 768 + hh * 64 + cs;
            kr0 = *(const uintx4*)kp;
            kr1 = *(const uintx4*)(kp + (size_t)32 * QKVG_N);
            const u16* vp = vTg + (size_t)(hh * 64 + rs) * 4096 + kb + cs;
            vr0 = *(const uintx4*)vp;
            vr1 = *(const uintx4*)(vp + (size_t)32 * 4096);
        }
        const bool edge = (tile == 1) | (tile == 9);
        #pragma unroll
        for (int kg2 = 0; kg2 < 2; ++kg2) {
            floatx4 sf[2];
            {
                halfx8 ka0 = *(const halfx8*)&ks[kg2 * 32 + qi][g * 8];
                halfx8 ka1 = *(const halfx8*)&ks[kg2 * 32 + qi][32 + g * 8];
                floatx4 z = (floatx4){0.f, 0.f, 0.f, 0.f};
                z = __builtin_amdgcn_mfma_f32_16x16x32_f16(ka0, qf0, z, 0, 0, 0);
                sf[0] = __builtin_amdgcn_mfma_f32_16x16x32_f16(ka1, qf1, z, 0, 0, 0);
            }
            {
                halfx8 kb0 = *(const halfx8*)&ks[kg2 * 32 + 16 + qi][g * 8];
                halfx8 kb1 = *(const halfx8*)&ks[kg2 * 32 + 16 + qi][32 + g * 8];
                floatx4 z = (floatx4){0.f, 0.f, 0.f, 0.f};
                z = __builtin_amdgcn_mfma_f32_16x16x32_f16(kb0, qf0, z, 0, 0, 0);
                sf[1] = __builtin_amdgcn_mfma_f32_16x16x32_f16(kb1, qf1, z, 0, 0, 0);
            }
            float p8[8];
            float mloc = -1e30f;
            #pragma unroll
            for (int f = 0; f < 2; ++f)
                #pragma unroll
                for (int r = 0; r < 4; ++r) {
                    int kl = kg2 * 32 + f * 16 + g * 4 + r;
                    float sc = sf[f][r] * 0.125f;
                    if (edge) {
                        int dd = kbase + kl - sq;
                        if (dd > 256 || dd < -256) sc = -1e30f;
                    }
                    p8[f * 4 + r] = sc;
                    mloc = fmaxf(mloc, sc);
                }
            mloc = fmaxf(mloc, __shfl_xor(mloc, 16));
            mloc = fmaxf(mloc, __shfl_xor(mloc, 32));
            float mnew = fmaxf(mrun, mloc);
            float alpha = __expf(mrun - mnew);
            mrun = mnew;
            float ls = 0.f;
            #pragma unroll
            for (int i = 0; i < 8; ++i) { float p = __expf(p8[i] - mnew); p8[i] = p; ls += p; }
            ls += __shfl_xor(ls, 16);
            ls += __shfl_xor(ls, 32);
            lrun = lrun * alpha + ls;
            u16x4 w0, w1;
            #pragma unroll
            for (int r = 0; r < 4; ++r) { w0[r] = f2h(p8[r]); w1[r] = f2h(p8[4 + r]); }
            *(u16x4*)&pbuf[w][qi][g * 4] = w0;
            *(u16x4*)&pbuf[w][qi][16 + g * 4] = w1;
            float al[4];
            #pragma unroll
            for (int r = 0; r < 4; ++r) al[r] = __shfl(alpha, g * 4 + r);
            #pragma unroll
            for (int dt = 0; dt < 4; ++dt)
                #pragma unroll
                for (int r = 0; r < 4; ++r) acc[dt][r] *= al[r];
            halfx8 pf = *(const halfx8*)&pbuf[w][qi][g * 8];
            #pragma unroll
            for (int dt = 0; dt < 4; ++dt) {
                halfx8 vb = *(const halfx8*)&vt[dt * 16 + qi][kg2 * 32 + g * 8];
                acc[dt] = __builtin_amdgcn_mfma_f32_16x16x32_f16(pf, vb, acc[dt], 0, 0, 0);
            }
        }
    }

    float inv = 1.f / lrun;
    float li[4];
    #pragma unroll
    for (int r = 0; r < 4; ++r) li[r] = __shfl(inv, g * 4 + r);
    #pragma unroll
    for (int dt = 0; dt < 4; ++dt)
        #pragma unroll
        for (int r = 0; r < 4; ++r) {
            int s = q0w + g * 4 + r;
            aob[(size_t)s * 768 + hh * 64 + dt * 16 + qi] = f2h(acc[dt][r] * li[r]);
        }

    // ---- fused global-attention merge (blocks owning GPOS row qb*64) ----
    if ((qb & 7) == 0) {
        __syncthreads();                       // this block's aob stores drained
        if (t < 64) {
            int gq = qb >> 3;                  // GPOS row = gq*512 = qb*64
            float M = -1e30f;
            #pragma unroll 4
            for (int c = 0; c < 32; ++c)
                M = fmaxf(M, pm[((size_t)hh * 32 + c) * 8 + gq]);
            float L = 0.f, o = 0.f;
            #pragma unroll 4
            for (int c = 0; c < 32; ++c) {
                float wz = __expf(pm[((size_t)hh * 32 + c) * 8 + gq] - M);
                L += pl[((size_t)hh * 32 + c) * 8 + gq] * wz;
                o += wz * pacc[(((size_t)hh * 32 + c) * 8 + gq) * 64 + t];
            }
            aob[(size_t)(gq * 512) * 768 + hh * 64 + t] = f2h(o / L);
        }
    }
}

// ---------------------------------------------------------------------------
// Embedding + LN, vectorized: 192 threads x float4. fp16 hidden state.
// ---------------------------------------------------------------------------
__global__ __launch_bounds__(192) void embed_ln_k(
    const int* __restrict__ x, const float* __restrict__ wemb, const float* __restrict__ pemb,
    const float* __restrict__ gs, const float* __restrict__ gb,
    u16* __restrict__ hh)
{
    int s = blockIdx.x, t = threadIdx.x;
    int w = s >> 9, p = s & 511;
    int id = (p == 0) ? 0 : x[w * 511 + p - 1];
    size_t off = (size_t)s * 768 + t * 4;
    floatx4 a = *(const floatx4*)(wemb + (size_t)id * 768 + t * 4);
    floatx4 b = *(const floatx4*)(pemb + off);
    floatx4 v;
    #pragma unroll
    for (int i = 0; i < 4; i++) v[i] = a[i] + b[i];
    float sum = v[0] + v[1] + v[2] + v[3];
    float sq = v[0] * v[0] + v[1] * v[1] + v[2] * v[2] + v[3] * v[3];
    #pragma unroll
    for (int o = 32; o > 0; o >>= 1) {
        sum += __shfl_down(sum, o); sq += __shfl_down(sq, o);
    }
    __shared__ float rs_[3], rq_[3];
    if ((t & 63) == 0) { rs_[t >> 6] = sum; rq_[t >> 6] = sq; }
    __syncthreads();
    float S = rs_[0] + rs_[1] + rs_[2];
    float Q = rq_[0] + rq_[1] + rq_[2];
    float mean = S * (1.f / 768.f);
    float inv = rsqrtf(Q * (1.f / 768.f) - mean * mean + 1e-5f);
    floatx4 g4 = *(const floatx4*)(gs + t * 4);
    floatx4 b4 = *(const floatx4*)(gb + t * 4);
    u16x4 oh;
    #pragma unroll
    for (int i = 0; i < 4; i++) {
        float y = (v[i] - mean) * inv * g4[i] + b4[i];
        oh[i] = f2h(y);
    }
    *(u16x4*)(hh + off) = oh;
}

// oh = LN(xa + sum_z yh[z]): all fp16; xa in-place ok. 192 thr x float4.
__global__ __launch_bounds__(192) void ln_resid_k(
    const u16* __restrict__ xa, const u16* __restrict__ yh,
    const float* __restrict__ gs, const float* __restrict__ gb,
    u16* __restrict__ oh)
{
    int s = blockIdx.x, t = threadIdx.x;      // t in [0,192)
    size_t off = (size_t)s * 768 + t * 4;
    u16x4 xa4 = *(const u16x4*)(xa + off);
    floatx4 v;
    #pragma unroll
    for (int i = 0; i < 4; i++) v[i] = h2f(xa4[i]);
    #pragma unroll
    for (int z = 0; z < 4; z++) {
        u16x4 b = *(const u16x4*)(yh + (size_t)z * 4096 * 768 + off);
        #pragma unroll
        for (int i = 0; i < 4; i++) v[i] += h2f(b[i]);
    }
    float sum = v[0] + v[1] + v[2] + v[3];
    float sq = v[0] * v[0] + v[1] * v[1] + v[2] * v[2] + v[3] * v[3];
    #pragma unroll
    for (int o = 32; o > 0; o >>= 1) {
        sum += __shfl_down(sum, o); sq += __shfl_down(sq, o);
    }
    __shared__ float rs_[3], rq_[3];
    if ((t & 63) == 0) { rs_[t >> 6] = sum; rq_[t >> 6] = sq; }
    __syncthreads();
    float S = rs_[0] + rs_[1] + rs_[2];
    float Q = rq_[0] + rq_[1] + rq_[2];
    float mean = S * (1.f / 768.f);
    float inv = rsqrtf(Q * (1.f / 768.f) - mean * mean + 1e-5f);
    floatx4 g4 = *(const floatx4*)(gs + t * 4);
    floatx4 b4 = *(const floatx4*)(gb + t * 4);
    u16x4 ohh;
    #pragma unroll
    for (int i = 0; i < 4; i++) {
        float y = (v[i] - mean) * inv * g4[i] + b4[i];
        ohh[i] = f2h(y);
    }
    *(u16x4*)(oh + off) = ohh;
}

// ---------------------------------------------------------------------------
// Global-token attention, pass 1: split-K partials (fp16 inputs).
// grid (12 heads, 32 key-chunks of 128), 256 threads.
// ---------------------------------------------------------------------------
__global__ __launch_bounds__(256) void attn_gpart_k(
    const u16* __restrict__ qkvg,
    float* __restrict__ pacc, float* __restrict__ pm, float* __restrict__ pl)
{
    const int hh = blockIdx.x, ck = blockIdx.y;
    const int t = threadIdx.x;
    __shared__ float qs[8][64];
    __shared__ __align__(16) u16 ks[128][72];   // +8 pad: stage writes c-free
    __shared__ __align__(16) u16 vs[128][64];   // read d-major -> conflict-free
    __shared__ float sc[8][128];
    __shared__ float mred[8], lred[8];

    for (int i = t; i < 512; i += 256) {
        int g = i >> 6, d = i & 63;
        qs[g][d] = h2f(qkvg[(size_t)(g * 512) * QKVG_N + 3840 + hh * 64 + d]) * 0.125f;
    }
    const int s0 = ck * 128;
    for (int u = t; u < 1024; u += 256) {
        int r = u >> 3, c = u & 7;
        const u16* src = qkvg + (size_t)(s0 + r) * QKVG_N + hh * 64 + c * 8;
        *(uintx4*)&ks[r][c * 8] = *(const uintx4*)(src + 2304);
        *(uintx4*)&vs[r][c * 8] = *(const uintx4*)(src + 3072);
    }
    __syncthreads();

    // scores: thread (key = t&127) computes 4 queries (t>>7 selects 0-3 / 4-7)
    {
        int key = t & 127, q0 = (t >> 7) * 4;
        float a[4] = {0.f, 0.f, 0.f, 0.f};
        #pragma unroll
        for (int c = 0; c < 8; ++c) {
            uintx4 pk = *(const uintx4*)&ks[key][c * 8];
            const u16* uu = (const u16*)&pk;
            #pragma unroll
            for (int e = 0; e < 8; ++e) {
                float kv = h2f(uu[e]);
                #pragma unroll
                for (int q = 0; q < 4; ++q) a[q] += kv * qs[q0 + q][c * 8 + e];
            }
        }
        #pragma unroll
        for (int q = 0; q < 4; ++q) sc[q0 + q][key] = a[q];
    }
    __syncthreads();

    // chunk softmax: q = t>>5, 32 lanes/query, 4 keys each
    {
        int q = t >> 5, lq = t & 31;
        float m = -1e30f;
        #pragma unroll
        for (int i = 0; i < 4; ++i) m = fmaxf(m, sc[q][lq + i * 32]);
        #pragma unroll
        for (int o = 1; o < 32; o <<= 1) m = fmaxf(m, __shfl_xor(m, o));
        float ls = 0.f;
        #pragma unroll
        for (int i = 0; i < 4; ++i) {
            float p = __expf(sc[q][lq + i * 32] - m);
            sc[q][lq + i * 32] = p; ls += p;
        }
        #pragma unroll
        for (int o = 1; o < 32; o <<= 1) ls += __shfl_xor(ls, o);
        if (lq == 0) { mred[q] = m; lred[q] = ls; }
    }
    __syncthreads();

    // partial PV: thread (d = t&63, qb = t>>6) -> o[qb][d], o[qb+4][d]
    {
        int d = t & 63, qb = t >> 6;
        float a0 = 0.f, a1 = 0.f;
        #pragma unroll 4
        for (int s = 0; s < 128; ++s) {
            float v = h2f(vs[s][d]);
            a0 += sc[qb][s] * v;
            a1 += sc[qb + 4][s] * v;
        }
        float* pb = pacc + (((size_t)hh * 32 + ck) * 8) * 64;
        pb[qb * 64 + d] = a0;
        pb[(qb + 4) * 64 + d] = a1;
        if (t < 8) {
            pm[((size_t)hh * 32 + ck) * 8 + t] = mred[t];
            pl[((size_t)hh * 32 + ck) * 8 + t] = lred[t];
        }
    }
}

__global__ __launch_bounds__(128) void head_k(
    const u16* __restrict__ hh, const float* __restrict__ Wout,
    const float* __restrict__ bout, float* __restrict__ out)
{
    int g = blockIdx.x, n = threadIdx.x;
    __shared__ float hsh[768];
    for (int i = n; i < 768; i += 128) hsh[i] = h2f(hh[(size_t)(g * 512) * 768 + i]);
    __syncthreads();
    float a = 0.f;
    #pragma unroll 4
    for (int k = 0; k < 768; k++) a += hsh[k] * Wout[k * 128 + n];
    out[g * 128 + n] = a + bout[n];
}

// ---------------------------------------------------------------------------
extern "C" void kernel_launch(void* const* d_in, const int* in_sizes, int n_in,
                              void* d_out, int out_size, void* d_ws, size_t ws_size,
                              hipStream_t stream)
{
    (void)in_sizes; (void)n_in; (void)out_size; (void)ws_size;
    const int*   x    = (const int*)  d_in[0];
    const float* wemb = (const float*)d_in[1];
    const float* pemb = (const float*)d_in[2];
    const float* elns = (const float*)d_in[3];
    const float* elnb = (const float*)d_in[4];
    const float* Wq   = (const float*)d_in[5];
    const float* bq   = (const float*)d_in[6];
    const float* Wk   = (const float*)d_in[7];
    const float* bk   = (const float*)d_in[8];
    const float* Wv   = (const float*)d_in[9];
    const float* bv   = (const float*)d_in[10];
    const float* Wo   = (const float*)d_in[11];
    const float* bo   = (const float*)d_in[12];
    const float* Wqg  = (const float*)d_in[13];
    const float* bqg  = (const float*)d_in[14];
    const float* Wkg  = (const float*)d_in[15];
    const float* bkg  = (const float*)d_in[16];
    const float* Wvg  = (const float*)d_in[17];
    const float* bvg  = (const float*)d_in[18];
    const float* l1s  = (const float*)d_in[19];
    const float* l1b  = (const float*)d_in[20];
    const float* W1   = (const float*)d_in[21];
    const float* b1   = (const float*)d_in[22];
    const float* W2   = (const float*)d_in[23];
    const float* b2   = (const float*)d_in[24];
    const float* l2s  = (const float*)d_in[25];
    const float* l2b  = (const float*)d_in[26];
    const float* Wout = (const float*)d_in[27];
    const float* boutp= (const float*)d_in[28];

    char* W = (char*)d_ws;
    u16*   hh    = (u16*)  (W);                  // [4096][768]  fp16 hidden
    u16*   qkvg  = (u16*)  (W + 18874368);       // [4096][4608] fp16
    u16*   ff1b  = (u16*)  (W + 18874368);       // [4096][3072] fp16 (reuses
                                                 //  qkvg after attn is done)
    u16*   vTg   = (u16*)  (W + 56623104);       // [768][4096]  fp16
    u16*   aob   = (u16*)  (W + 62914560);       // [4096][768]  fp16
    u16*   yh    = (u16*)  (W + 69206016);       // [4][4096][768] fp16 slabs
    float* pacc  = (float*)(W + 119537664);      // [12][32][8][64] fp32
    float* pmw   = (float*)(W + 120324096);      // [12][32][8]     fp32
    float* plw   = (float*)(W + 120336384);      // [12][32][8]     fp32
    float* bcatall = (float*)(W + 120348672);    // [12][4608]      fp32
    u16*   wTall = (u16*)  (W + 120569856);      // [12] x 8847360 u16 (fp16)

    // All-layer weight prep (one launch, single-buffer LDS, NT streams)
    prep_weights_k<<<6696, 256, 0, stream>>>(
        Wq, Wk, Wv, Wkg, Wvg, Wqg, Wo, W1, W2,
        bq, bk, bv, bkg, bvg, bqg, wTall, bcatall);

    embed_ln_k<<<4096, 192, 0, stream>>>(x, wemb, pemb, elns, elnb, hh);

    for (int l = 0; l < NL; ++l) {
        u16* wTl      = wTall + (size_t)l * 8847360;
        u16* wqkvgT_l = wTl;
        u16* woT_l    = wTl + 3538944;
        u16* w1T_l    = woT_l + 589824;
        u16* w2T_l    = w1T_l + 2359296;
        float* bcat_l = bcatall + (size_t)l * 4608;
        const float* bo_l  = bo  + (size_t)l * 768;
        const float* b1_l  = b1  + (size_t)l * 3072;
        const float* b2_l  = b2  + (size_t)l * 768;
        const float* l1s_l = l1s + (size_t)l * 768;
        const float* l1b_l = l1b + (size_t)l * 768;
        const float* l2s_l = l2s + (size_t)l * 768;
        const float* l2b_l = l2b + (size_t)l * 768;

        // fused q/k/v/kg/vg/qg projection -> fp16 [4096][4608] (+ vTg fused,
        // dead v/qg-row writes skipped). MINW=4: 1008 working blocks fit in
        // one resident wave (4 blocks/CU x 256 CUs = 1024 slots).
        gemm_k<0, 0, 1, 1, 1, 0, 4><<<dim3(32, 36), 256, 0, stream>>>(
            hh, wqkvgT_l, bcat_l, (float*)nullptr, qkvg, vTg, QKVG_N, 768, 768, 768);

        // global-attention partials FIRST (kernel boundary -> visible to the
        // fused merge in attn_local)
        attn_gpart_k<<<dim3(12, 32), 256, 0, stream>>>(qkvg, pacc, pmw, plw);

        attn_local_k<<<dim3(64, 12), 256, 0, stream>>>(qkvg, vTg, aob, pacc, pmw, plw);

        // attention output proj, split-K x4 (K=768/4=192) -> fp16 slabs
        gemm_k<0, 0, 0, 0, 0, 1, 3><<<dim3(32, 6, 4), 256, 0, stream>>>(
            aob, woT_l, bo_l, (float*)nullptr, yh, (u16*)nullptr, 768, 192, 768, 768);
        ln_resid_k<<<4096, 192, 0, stream>>>(hh, yh, l1s_l, l1b_l, hh);

        gemm_k<1, 0, 1, 0, 0, 0, 3><<<dim3(32, 24), 256, 0, stream>>>(
            hh, w1T_l, b1_l, (float*)nullptr, ff1b, (u16*)nullptr, 3072, 768, 768, 768);
        // FFN down proj, split-K x4 (K=3072/4=768) -> fp16 slabs
        gemm_k<0, 0, 0, 0, 0, 1, 3><<<dim3(32, 6, 4), 256, 0, stream>>>(
            ff1b, w2T_l, b2_l, (float*)nullptr, yh, (u16*)nullptr, 768, 768, 3072, 3072);
        ln_resid_k<<<4096, 192, 0, stream>>>(hh, yh, l2s_l, l2b_l, hh);
    }

    head_k<<<8, 128, 0, stream>>>(hh, Wout, boutp, (float*)d_out);
}